// Round 20
// baseline (396.855 us; speedup 1.0000x reference)
//
#include <hip/hip_runtime.h>
#include <hip/hip_bf16.h>

#define TT 2048
#define HD 2048
#define ID 2048
#define NE 8

typedef __attribute__((ext_vector_type(8))) short short8;
typedef __attribute__((ext_vector_type(4))) float f4;

__device__ __forceinline__ unsigned short b16(float f){
  union { __hip_bfloat16 b; unsigned short u; } x;
  x.b = __float2bfloat16(f);
  return x.u;
}
__device__ __forceinline__ unsigned pk2(float lo, float hi){
  return (unsigned)b16(lo) | ((unsigned)b16(hi) << 16);
}
__device__ __forceinline__ float gelu_t(float x){
  float y = 0.7978845608028654f * (x + 0.044715f * x * x * x);
  float t = 1.0f - 2.0f / (__expf(2.0f * y) + 1.0f);
  return 0.5f * x * (1.0f + t);
}
__device__ __forceinline__ void glds16(const void* g, void* l){
  __builtin_amdgcn_global_load_lds(
      (const __attribute__((address_space(1))) unsigned*)g,
      (__attribute__((address_space(3))) unsigned*)l, 16, 0, 0);
}
__device__ __forceinline__ void softbar(){
  asm volatile("s_waitcnt lgkmcnt(0)" ::: "memory");
  __builtin_amdgcn_s_barrier();
  __builtin_amdgcn_sched_barrier(0);
}
__device__ __forceinline__ int swzB2(int np){ return (((np >> 2) & 7) ^ ((np & 3) << 1)) & 7; }

// ---------------- X fp32 -> bf16 ----------------
__global__ void k_cvtx(const float* __restrict__ X, __hip_bfloat16* __restrict__ Xb){
  int i = blockIdx.x * 256 + threadIdx.x;
  const f4* src = (const f4*)X + (size_t)i * 2;
  f4 a = src[0], b = src[1];
  uint4 o = { pk2(a[0],a[1]), pk2(a[2],a[3]), pk2(b[0],b[1]), pk2(b[2],b[3]) };
  ((uint4*)Xb)[i] = o;
}

// ---------------- routing ----------------
__global__ void k_route(const float* __restrict__ lg, const float* __restrict__ sc,
                        int* __restrict__ rid, float* __restrict__ rw){
  int t = blockIdx.x * blockDim.x + threadIdx.x;
  if (t >= TT) return;
  float l[NE];
#pragma unroll
  for (int e = 0; e < NE; e++) l[e] = lg[t * NE + e];
  float mx = l[0];
#pragma unroll
  for (int e = 1; e < NE; e++) mx = fmaxf(mx, l[e]);
  float p[NE];
#pragma unroll
  for (int e = 0; e < NE; e++) p[e] = __expf(l[e] - mx);
  int i0 = 0; float b0 = l[0];
#pragma unroll
  for (int e = 1; e < NE; e++) if (l[e] > b0){ b0 = l[e]; i0 = e; }
  int i1 = -1; float b1 = -1e30f;
#pragma unroll
  for (int e = 0; e < NE; e++) if (e != i0 && l[e] > b1){ b1 = l[e]; i1 = e; }
  float p0 = p[i0], p1 = p[i1];
  float rn = p0 + p1; rn = (rn > 0.f) ? rn : 1.f;
  rw[t*2]   = p0 / rn * sc[i0];
  rw[t*2+1] = p1 / rn * sc[i1];
  rid[t*2]  = i0;
  rid[t*2+1]= i1;
}

// ---------------- deterministic per-expert compaction (+ zero work-queue counters) ----------
__global__ void k_lists(const int* __restrict__ rid, const float* __restrict__ rw,
                        int* __restrict__ row_tok, float* __restrict__ row_w,
                        int* __restrict__ off, int* __restrict__ qcnt){
  int lane = threadIdx.x;            // 64 threads
  if (lane < 2) qcnt[lane] = 0;      // gu / dn tile counters
  int ids[64]; float wv[64];
#pragma unroll
  for (int i = 0; i < 64; i++) ids[i] = rid[i * 64 + lane];
#pragma unroll
  for (int i = 0; i < 64; i++) wv[i] = rw[i * 64 + lane];
  int cnt[NE];
#pragma unroll
  for (int e = 0; e < NE; e++) cnt[e] = 0;
#pragma unroll
  for (int i = 0; i < 64; i++){
#pragma unroll
    for (int e = 0; e < NE; e++)
      cnt[e] += __popcll(__ballot(ids[i] == e));
  }
  int offs[NE + 1]; offs[0] = 0;
#pragma unroll
  for (int e = 0; e < NE; e++) offs[e + 1] = offs[e] + cnt[e];
  if (lane == 0){
#pragma unroll
    for (int e = 0; e <= NE; e++) off[e] = offs[e];
  }
  int run[NE];
#pragma unroll
  for (int e = 0; e < NE; e++) run[e] = offs[e];
  unsigned long long ltm = (1ULL << lane) - 1ULL;
#pragma unroll
  for (int i = 0; i < 64; i++){
    int id = ids[i];
    int tok = (i * 64 + lane) >> 1;
#pragma unroll
    for (int e = 0; e < NE; e++){
      unsigned long long m = __ballot(id == e);
      if (id == e){
        int pos = run[e] + __popcll(m & ltm);
        row_tok[pos] = tok;
        row_w[pos]   = wv[i];
      }
      run[e] += __popcll(m);
    }
  }
}

// ================= FAST PATH: persistent-block work queue over verified r16 body ============
// 768 blocks (= 256 CU x 3 resident, exact LDS fit at 49KB). Tiles pulled via device-scope
// atomicAdd; tile order keeps the 5 mt-sharers of each (e,nt) B-panel adjacent in time.
// K-loop schedule unchanged (drain-at-ds_write; no manual vmcnt).

// -------- gate+up: ONE grouped GEMM, g/u 32-col interleave in LDS n', fused gelu*w --------
__global__ __launch_bounds__(256, 3)
void k_gu_f(const __hip_bfloat16* __restrict__ Xb, const float* __restrict__ Wg,
            const float* __restrict__ Wu, const int* __restrict__ row_tok,
            const float* __restrict__ row_w, const int* __restrict__ off,
            int* __restrict__ qcnt, __hip_bfloat16* __restrict__ hbuf){
  __shared__ __align__(16) char sA[2][16384];  // [128 m][64 k] bf16, slot^=(m&7), dbuf
  __shared__ __align__(16) char sB[16384];     // [128 n'][64 k] bf16, slot^=swzB2(n')
  __shared__ int s_tok[128];
  __shared__ float s_w[128];
  __shared__ int s_tile;

  const int tid = threadIdx.x;
  const int wid = tid >> 6, lane = tid & 63;

  // ---- lane-constant setup (hoisted out of the tile loop) ----
  const int sw = (((lane & 7) ^ (lane >> 3)) & 7) << 4;
  const int m2 = tid >> 7, tt = tid & 127;
  const int n0 = (tt & 15) * 4;              // 0..60 within 64-col panel
  const int s0 = tt >> 4;                    // k-slot 0..7, k0 = s0*8
  int bw[4];
#pragma unroll
  for (int j = 0; j < 4; j++){
    int n  = n0 + j;
    int np = (n >> 5) * 64 + (n & 31) + m2 * 32;            // gu-interleaved LDS row
    bw[j] = np * 128 + (((s0 ^ swzB2(np)) & 7) << 4);
  }
  const int wm = wid >> 1, wn = wid & 1;     // 2x2 waves, wave = 64m x 64n'
  const int kg = lane >> 4, ln = lane & 15;
  int aoff[4], boff[4];
#pragma unroll
  for (int f = 0; f < 4; f++){
    int m = wm * 64 + f * 16 + ln;
    aoff[f] = m * 128 + (((kg ^ (m & 7)) & 7) << 4);
    int n = wn * 64 + f * 16 + ln;
    boff[f] = n * 128 + (((kg ^ swzB2(n)) & 7) << 4);
  }

  for (;;){
    if (tid == 0) s_tile = atomicAdd(qcnt, 1);
    __syncthreads();                         // converge (prev tile epilogue done) + broadcast
    const int tile = s_tile;
    if (tile >= 1280) break;
    const int e  = tile & 7;                 // 1280 = e(&7) x (nt*5 + mt): mt-sharers adjacent
    const int t  = tile >> 3;
    const int mt = t % 5;
    const int nt = t / 5;                    // 0..31
    const int o0 = off[e], cnt = off[e + 1] - o0;
    if (mt * 128 >= cnt) continue;           // dead tile (uniform) -> grab another
    const int p0 = o0 + mt * 128;
    const int cntL = min(128, cnt - mt * 128);

    if (tid < 128){
      int p = min(p0 + tid, TT*2 - 1);
      s_tok[tid] = row_tok[p];
      s_w[tid]   = row_w[p];
    }
    __syncthreads();

    const char* asrc[4];
#pragma unroll
    for (int i = 0; i < 4; i++){
      int r = (wid * 4 + i) * 8 + (lane >> 3);              // 0..127
      asrc[i] = (const char*)Xb + (size_t)s_tok[r] * 4096 + sw;
    }
    const float* wsrc = (m2 ? Wu : Wg) + (size_t)e * HD * ID
                      + (size_t)(s0 * 8) * ID + (size_t)nt * 64 + n0;

    f4 acc[4][4];
#pragma unroll
    for (int a = 0; a < 4; a++)
#pragma unroll
      for (int b = 0; b < 4; b++) acc[a][b] = f4{0,0,0,0};

    // prologue: A(0) -> sA[0]; B(0) -> regs
#pragma unroll
    for (int i = 0; i < 4; i++) glds16(asrc[i], &sA[0][0] + (wid * 4 + i) * 1024);
    f4 rk[8];
#pragma unroll
    for (int i = 0; i < 8; i++) rk[i] = *(const f4*)(wsrc + (size_t)i * ID);

    for (int kt = 0; kt < 32; ++kt){
      softbar();                                // all waves done reading sB(kt-1), sA[alt]
#pragma unroll
      for (int j = 0; j < 4; j++){
        *(uint4*)(sB + bw[j]) = uint4{ pk2(rk[0][j], rk[1][j]), pk2(rk[2][j], rk[3][j]),
                                       pk2(rk[4][j], rk[5][j]), pk2(rk[6][j], rk[7][j]) };
      }
      __builtin_amdgcn_sched_barrier(0);
      if (kt + 1 < 32){
        const int _o = (kt + 1) * 128;
        char* dst = &sA[(kt + 1) & 1][0] + (wid * 4) * 1024;
#pragma unroll
        for (int i = 0; i < 4; i++) glds16(asrc[i] + _o, dst + i * 1024);
      }
      __builtin_amdgcn_sched_barrier(0);
      if (kt + 1 < 32){
        const float* p = wsrc + (size_t)(kt + 1) * 64 * ID;
#pragma unroll
        for (int i = 0; i < 8; i++) rk[i] = *(const f4*)(p + (size_t)i * ID);
      }
      __builtin_amdgcn_sched_barrier(0);
      asm volatile("s_waitcnt lgkmcnt(0)" ::: "memory");   // sB(kt) visible
      __builtin_amdgcn_s_barrier();
      __builtin_amdgcn_sched_barrier(0);
      const char* A = &sA[kt & 1][0];
#pragma unroll
      for (int ks = 0; ks < 2; ks++){
        const int kx = ks * 64;
        short8 af[4], bf[4];
#pragma unroll
        for (int f = 0; f < 4; f++) af[f] = *(const short8*)(A + (aoff[f] ^ kx));
#pragma unroll
        for (int f = 0; f < 4; f++) bf[f] = *(const short8*)(sB + (boff[f] ^ kx));
#pragma unroll
        for (int fn = 0; fn < 4; fn++)
#pragma unroll
          for (int fm = 0; fm < 4; fm++)
            acc[fm][fn] = __builtin_amdgcn_mfma_f32_16x16x32_bf16(af[fm], bf[fn], acc[fm][fn], 0, 0, 0);
      }
    }
    // epilogue: h = w * gelu(g) * u
#pragma unroll
    for (int fm = 0; fm < 4; fm++){
#pragma unroll
      for (int r = 0; r < 4; r++){
        int row = wm * 64 + fm * 16 + (lane >> 4) * 4 + r;
        if (row < cntL){
          float w = s_w[row];
          size_t base = (size_t)(p0 + row) * ID + (size_t)nt * 64 + wn * 32 + ln;
#pragma unroll
          for (int fn = 0; fn < 2; fn++){
            float g = acc[fm][fn][r];
            float u = acc[fm][fn + 2][r];
            hbuf[base + fn * 16] = __float2bfloat16(w * gelu_t(g) * u);
          }
        }
      }
    }
  }
}

// -------- down: fused fp32 Wd staging + plain atomic scatter (w pre-applied in gu) --------
__global__ __launch_bounds__(256, 3)
void k_dn_f(const __hip_bfloat16* __restrict__ hbuf, const float* __restrict__ Wd,
            const int* __restrict__ row_tok, const int* __restrict__ off,
            int* __restrict__ qcnt, float* __restrict__ out){
  __shared__ __align__(16) char sA[2][16384];  // [128 m][64 k], dbuf
  __shared__ __align__(16) char sB[16384];     // [128 n][64 k], slot^=swzB2(n)
  __shared__ int s_tok[128];
  __shared__ int s_tile;

  const int tid = threadIdx.x;
  const int wid = tid >> 6, lane = tid & 63;

  const int sw = (((lane & 7) ^ (lane >> 3)) & 7) << 4;
  const int n0 = (tid & 31) * 4;             // 0..124
  const int s0 = tid >> 5;                   // 0..7, k0 = s0*8
  int bw[4];
#pragma unroll
  for (int j = 0; j < 4; j++){
    int np = n0 + j;
    bw[j] = np * 128 + (((s0 ^ swzB2(np)) & 7) << 4);
  }
  const int wm = wid >> 1, wn = wid & 1;
  const int kg = lane >> 4, ln = lane & 15;
  int aoff[4], boff[4];
#pragma unroll
  for (int f = 0; f < 4; f++){
    int m = wm * 64 + f * 16 + ln;
    aoff[f] = m * 128 + (((kg ^ (m & 7)) & 7) << 4);
    int n = wn * 64 + f * 16 + ln;
    boff[f] = n * 128 + (((kg ^ swzB2(n)) & 7) << 4);
  }

  for (;;){
    if (tid == 0) s_tile = atomicAdd(qcnt + 1, 1);
    __syncthreads();
    const int tile = s_tile;
    if (tile >= 640) break;
    const int e  = tile & 7;                 // 640 = e(&7) x (nt*5 + mt)
    const int t  = tile >> 3;
    const int mt = t % 5;
    const int nt = t / 5;                    // 0..15
    const int o0 = off[e], cnt = off[e + 1] - o0;
    if (mt * 128 >= cnt) continue;
    const int p0 = o0 + mt * 128;
    const int cntL = min(128, cnt - mt * 128);

    if (tid < 128){
      int p = min(p0 + tid, TT*2 - 1);
      s_tok[tid] = row_tok[p];
    }
    __syncthreads();

    const char* asrc[4];
#pragma unroll
    for (int i = 0; i < 4; i++){
      int r = (wid * 4 + i) * 8 + (lane >> 3);
      int p = min(p0 + r, TT*2 - 1);
      asrc[i] = (const char*)hbuf + (size_t)p * 4096 + sw;
    }
    const float* wsrc = Wd + (size_t)e * ID * HD + (size_t)(s0 * 8) * HD + (size_t)nt * 128 + n0;

    f4 acc[4][4];
#pragma unroll
    for (int a = 0; a < 4; a++)
#pragma unroll
      for (int b = 0; b < 4; b++) acc[a][b] = f4{0,0,0,0};

#pragma unroll
    for (int i = 0; i < 4; i++) glds16(asrc[i], &sA[0][0] + (wid * 4 + i) * 1024);
    f4 rk[8];
#pragma unroll
    for (int i = 0; i < 8; i++) rk[i] = *(const f4*)(wsrc + (size_t)i * HD);

    for (int kt = 0; kt < 32; ++kt){
      softbar();
#pragma unroll
      for (int j = 0; j < 4; j++){
        *(uint4*)(sB + bw[j]) = uint4{ pk2(rk[0][j], rk[1][j]), pk2(rk[2][j], rk[3][j]),
                                       pk2(rk[4][j], rk[5][j]), pk2(rk[6][j], rk[7][j]) };
      }
      __builtin_amdgcn_sched_barrier(0);
      if (kt + 1 < 32){
        const int _o = (kt + 1) * 128;
        char* dst = &sA[(kt + 1) & 1][0] + (wid * 4) * 1024;
#pragma unroll
        for (int i = 0; i < 4; i++) glds16(asrc[i] + _o, dst + i * 1024);
      }
      __builtin_amdgcn_sched_barrier(0);
      if (kt + 1 < 32){
        const float* p = wsrc + (size_t)(kt + 1) * 64 * HD;
#pragma unroll
        for (int i = 0; i < 8; i++) rk[i] = *(const f4*)(p + (size_t)i * HD);
      }
      __builtin_amdgcn_sched_barrier(0);
      asm volatile("s_waitcnt lgkmcnt(0)" ::: "memory");
      __builtin_amdgcn_s_barrier();
      __builtin_amdgcn_sched_barrier(0);
      const char* A = &sA[kt & 1][0];
#pragma unroll
      for (int ks = 0; ks < 2; ks++){
        const int kx = ks * 64;
        short8 af[4], bf[4];
#pragma unroll
        for (int f = 0; f < 4; f++) af[f] = *(const short8*)(A + (aoff[f] ^ kx));
#pragma unroll
        for (int f = 0; f < 4; f++) bf[f] = *(const short8*)(sB + (boff[f] ^ kx));
#pragma unroll
        for (int fn = 0; fn < 4; fn++)
#pragma unroll
          for (int fm = 0; fm < 4; fm++)
            acc[fm][fn] = __builtin_amdgcn_mfma_f32_16x16x32_bf16(af[fm], bf[fn], acc[fm][fn], 0, 0, 0);
      }
    }
#pragma unroll
    for (int fm = 0; fm < 4; fm++){
#pragma unroll
      for (int r = 0; r < 4; r++){
        int row = wm * 64 + fm * 16 + (lane >> 4) * 4 + r;
        if (row < cntL){
          int tok = s_tok[row];
          float* ob = out + (size_t)tok * HD + (size_t)nt * 128 + wn * 64 + ln;
#pragma unroll
          for (int fn = 0; fn < 4; fn++)
            atomicAdd(ob + fn * 16, acc[fm][fn][r]);
        }
      }
    }
  }
}

extern "C" void kernel_launch(void* const* d_in, const int* in_sizes, int n_in,
                              void* d_out, int out_size, void* d_ws, size_t ws_size,
                              hipStream_t stream){
  (void)in_sizes; (void)n_in; (void)out_size; (void)ws_size;
  const float* X  = (const float*)d_in[0];
  const float* RL = (const float*)d_in[1];
  const float* SC = (const float*)d_in[2];
  const float* Wg = (const float*)d_in[3];
  const float* Wu = (const float*)d_in[4];
  const float* Wd = (const float*)d_in[5];
  float* out = (float*)d_out;

  char* ws = (char*)d_ws;
  int*   rid     = (int*)(ws);
  float* rw      = (float*)(ws + 16384);
  int*   row_tok = (int*)(ws + 32768);
  float* row_w   = (float*)(ws + 49152);
  int*   off     = (int*)(ws + 65536);
  int*   qcnt    = (int*)(ws + 66048);
  __hip_bfloat16* hbuf = (__hip_bfloat16*)(ws + 66560);                      // 16 MiB
  __hip_bfloat16* Xb   = (__hip_bfloat16*)(ws + 66560 + 16777216ull);        // 8 MiB

  hipMemsetAsync(d_out, 0, (size_t)TT * HD * sizeof(float), stream);
  k_cvtx <<<2048, 256, 0, stream>>>(X, Xb);
  k_route<<<TT / 256, 256, 0, stream>>>(RL, SC, rid, rw);
  k_lists<<<1, 64, 0, stream>>>(rid, rw, row_tok, row_w, off, qcnt);
  k_gu_f<<<768, 256, 0, stream>>>(Xb, Wg, Wu, row_tok, row_w, off, qcnt, hbuf);
  k_dn_f<<<768, 256, 0, stream>>>(hbuf, Wd, row_tok, off, qcnt, out);
}

// Round 21
// 300.007 us; speedup vs baseline: 1.3228x; 1.3228x over previous
//
#include <hip/hip_runtime.h>
#include <hip/hip_bf16.h>

#define TT 2048
#define HD 2048
#define ID 2048
#define NE 8

typedef __attribute__((ext_vector_type(8))) short short8;
typedef __attribute__((ext_vector_type(4))) float f4;

__device__ __forceinline__ unsigned short b16(float f){
  union { __hip_bfloat16 b; unsigned short u; } x;
  x.b = __float2bfloat16(f);
  return x.u;
}
__device__ __forceinline__ unsigned pk2(float lo, float hi){
  return (unsigned)b16(lo) | ((unsigned)b16(hi) << 16);
}
__device__ __forceinline__ float gelu_t(float x){
  float y = 0.7978845608028654f * (x + 0.044715f * x * x * x);
  float t = 1.0f - 2.0f / (__expf(2.0f * y) + 1.0f);
  return 0.5f * x * (1.0f + t);
}
__device__ __forceinline__ void glds16(const void* g, void* l){
  __builtin_amdgcn_global_load_lds(
      (const __attribute__((address_space(1))) unsigned*)g,
      (__attribute__((address_space(3))) unsigned*)l, 16, 0, 0);
}
__device__ __forceinline__ void softbar(){
  asm volatile("s_waitcnt lgkmcnt(0)" ::: "memory");
  __builtin_amdgcn_s_barrier();
  __builtin_amdgcn_sched_barrier(0);
}
__device__ __forceinline__ int swzB2(int np){ return (((np >> 2) & 7) ^ ((np & 3) << 1)) & 7; }

// ---------------- X fp32 -> bf16 ----------------
__global__ void k_cvtx(const float* __restrict__ X, __hip_bfloat16* __restrict__ Xb){
  int i = blockIdx.x * 256 + threadIdx.x;
  const f4* src = (const f4*)X + (size_t)i * 2;
  f4 a = src[0], b = src[1];
  uint4 o = { pk2(a[0],a[1]), pk2(a[2],a[3]), pk2(b[0],b[1]), pk2(b[2],b[3]) };
  ((uint4*)Xb)[i] = o;
}

// ---------------- routing ----------------
__global__ void k_route(const float* __restrict__ lg, const float* __restrict__ sc,
                        int* __restrict__ rid, float* __restrict__ rw){
  int t = blockIdx.x * blockDim.x + threadIdx.x;
  if (t >= TT) return;
  float l[NE];
#pragma unroll
  for (int e = 0; e < NE; e++) l[e] = lg[t * NE + e];
  float mx = l[0];
#pragma unroll
  for (int e = 1; e < NE; e++) mx = fmaxf(mx, l[e]);
  float p[NE];
#pragma unroll
  for (int e = 0; e < NE; e++) p[e] = __expf(l[e] - mx);
  int i0 = 0; float b0 = l[0];
#pragma unroll
  for (int e = 1; e < NE; e++) if (l[e] > b0){ b0 = l[e]; i0 = e; }
  int i1 = -1; float b1 = -1e30f;
#pragma unroll
  for (int e = 0; e < NE; e++) if (e != i0 && l[e] > b1){ b1 = l[e]; i1 = e; }
  float p0 = p[i0], p1 = p[i1];
  float rn = p0 + p1; rn = (rn > 0.f) ? rn : 1.f;
  rw[t*2]   = p0 / rn * sc[i0];
  rw[t*2+1] = p1 / rn * sc[i1];
  rid[t*2]  = i0;
  rid[t*2+1]= i1;
}

// ---------------- deterministic per-expert compaction ----------------
__global__ void k_lists(const int* __restrict__ rid, const float* __restrict__ rw,
                        int* __restrict__ row_tok, float* __restrict__ row_w,
                        int* __restrict__ off){
  int lane = threadIdx.x;            // 64 threads
  int ids[64]; float wv[64];
#pragma unroll
  for (int i = 0; i < 64; i++) ids[i] = rid[i * 64 + lane];
#pragma unroll
  for (int i = 0; i < 64; i++) wv[i] = rw[i * 64 + lane];
  int cnt[NE];
#pragma unroll
  for (int e = 0; e < NE; e++) cnt[e] = 0;
#pragma unroll
  for (int i = 0; i < 64; i++){
#pragma unroll
    for (int e = 0; e < NE; e++)
      cnt[e] += __popcll(__ballot(ids[i] == e));
  }
  int offs[NE + 1]; offs[0] = 0;
#pragma unroll
  for (int e = 0; e < NE; e++) offs[e + 1] = offs[e] + cnt[e];
  if (lane == 0){
#pragma unroll
    for (int e = 0; e <= NE; e++) off[e] = offs[e];
  }
  int run[NE];
#pragma unroll
  for (int e = 0; e < NE; e++) run[e] = offs[e];
  unsigned long long ltm = (1ULL << lane) - 1ULL;
#pragma unroll
  for (int i = 0; i < 64; i++){
    int id = ids[i];
    int tok = (i * 64 + lane) >> 1;
#pragma unroll
    for (int e = 0; e < NE; e++){
      unsigned long long m = __ballot(id == e);
      if (id == e){
        int pos = run[e] + __popcll(m & ltm);
        row_tok[pos] = tok;
        row_w[pos]   = wv[i];
      }
      run[e] += __popcll(m);
    }
  }
}

// ================= FAST PATH (round-19 verified: best = 302 us) =============================
// e = bid&7 (expert->XCD pin keeps A- and B-panel L2 reuse; all remaps regressed).
// Schedule per iter (drain-at-ds_write; NO manual vmcnt):
//   softbar -> ds_write B(kt) [dep-wait retires A(kt) issued 1 iter ago] -> glds A(kt+1)
//   -> load B(kt+1) regs -> lgkmcnt(0)+barrier -> MFMA from sA[kt&1].
// w-prescale: gu epilogue writes h = w * gelu(g) * u; dn is then a plain GEMM+atomicAdd.

// -------- gate+up: ONE grouped GEMM, g/u 32-col interleave in LDS n', fused gelu*w --------
__global__ __launch_bounds__(256, 3)
void k_gu_f(const __hip_bfloat16* __restrict__ Xb, const float* __restrict__ Wg,
            const float* __restrict__ Wu, const int* __restrict__ row_tok,
            const float* __restrict__ row_w, const int* __restrict__ off,
            __hip_bfloat16* __restrict__ hbuf){
  __shared__ __align__(16) char sA[2][16384];  // [128 m][64 k] bf16, slot^=(m&7), dbuf
  __shared__ __align__(16) char sB[16384];     // [128 n'][64 k] bf16, slot^=swzB2(n')
  __shared__ int s_tok[128];
  __shared__ float s_w[128];

  const int bid = blockIdx.x;                // 1280 = e(bid&7) x 5mt x 32nt, mt inner
  const int e  = bid & 7;
  const int t  = bid >> 3;
  const int mt = t % 5;
  const int nt = t / 5;                      // 0..31: 64 g-cols + 64 u-cols per tile
  const int o0 = off[e], cnt = off[e + 1] - o0;
  if (mt * 128 >= cnt) return;
  const int p0 = o0 + mt * 128;
  const int cntL = min(128, cnt - mt * 128);
  const int tid = threadIdx.x;
  const int wid = tid >> 6, lane = tid & 63;

  if (tid < 128){
    int p = min(p0 + tid, TT*2 - 1);
    s_tok[tid] = row_tok[p];
    s_w[tid]   = row_w[p];
  }
  __syncthreads();

  // A staging sources (glds16, inverse-swizzled source)
  const int sw = (((lane & 7) ^ (lane >> 3)) & 7) << 4;
  const char* asrc[4];
#pragma unroll
  for (int i = 0; i < 4; i++){
    int r = (wid * 4 + i) * 8 + (lane >> 3);                // 0..127
    asrc[i] = (const char*)Xb + (size_t)s_tok[r] * 4096 + sw;
  }
  // B staging: thread -> matrix m2 (0=g,1=u), 4 n x 8 consecutive k
  const int m2 = tid >> 7, tt = tid & 127;
  const int n0 = (tt & 15) * 4;              // 0..60 within 64-col panel
  const int s0 = tt >> 4;                    // k-slot 0..7, k0 = s0*8
  const float* wsrc = (m2 ? Wu : Wg) + (size_t)e * HD * ID
                    + (size_t)(s0 * 8) * ID + (size_t)nt * 64 + n0;
  int bw[4];
#pragma unroll
  for (int j = 0; j < 4; j++){
    int n  = n0 + j;
    int np = (n >> 5) * 64 + (n & 31) + m2 * 32;            // gu-interleaved LDS row
    bw[j] = np * 128 + (((s0 ^ swzB2(np)) & 7) << 4);
  }
  // fragment read offsets
  const int wm = wid >> 1, wn = wid & 1;     // 2x2 waves, wave = 64m x 64n'
  const int kg = lane >> 4, ln = lane & 15;
  int aoff[4], boff[4];
#pragma unroll
  for (int f = 0; f < 4; f++){
    int m = wm * 64 + f * 16 + ln;
    aoff[f] = m * 128 + (((kg ^ (m & 7)) & 7) << 4);
    int n = wn * 64 + f * 16 + ln;
    boff[f] = n * 128 + (((kg ^ swzB2(n)) & 7) << 4);
  }

  f4 acc[4][4];
#pragma unroll
  for (int a = 0; a < 4; a++)
#pragma unroll
    for (int b = 0; b < 4; b++) acc[a][b] = f4{0,0,0,0};

  // prologue: A(0) -> sA[0]; B(0) -> regs
#pragma unroll
  for (int i = 0; i < 4; i++) glds16(asrc[i], &sA[0][0] + (wid * 4 + i) * 1024);
  f4 rk[8];
#pragma unroll
  for (int i = 0; i < 8; i++) rk[i] = *(const f4*)(wsrc + (size_t)i * ID);

  for (int kt = 0; kt < 32; ++kt){
    softbar();                                  // all waves done reading sB(kt-1), sA[alt]
    // ds_write B(kt): dep-wait drains all outstanding loads incl. A(kt) (1 iter old)
#pragma unroll
    for (int j = 0; j < 4; j++){
      *(uint4*)(sB + bw[j]) = uint4{ pk2(rk[0][j], rk[1][j]), pk2(rk[2][j], rk[3][j]),
                                     pk2(rk[4][j], rk[5][j]), pk2(rk[6][j], rk[7][j]) };
    }
    __builtin_amdgcn_sched_barrier(0);
    // glds A(kt+1) -> sA[alt]
    if (kt + 1 < 32){
      const int _o = (kt + 1) * 128;
      char* dst = &sA[(kt + 1) & 1][0] + (wid * 4) * 1024;
#pragma unroll
      for (int i = 0; i < 4; i++) glds16(asrc[i] + _o, dst + i * 1024);
    }
    __builtin_amdgcn_sched_barrier(0);
    // load B(kt+1) regs
    if (kt + 1 < 32){
      const float* p = wsrc + (size_t)(kt + 1) * 64 * ID;
#pragma unroll
      for (int i = 0; i < 8; i++) rk[i] = *(const f4*)(p + (size_t)i * ID);
    }
    __builtin_amdgcn_sched_barrier(0);
    asm volatile("s_waitcnt lgkmcnt(0)" ::: "memory");   // sB(kt) visible; no vmcnt
    __builtin_amdgcn_s_barrier();
    __builtin_amdgcn_sched_barrier(0);
    const char* A = &sA[kt & 1][0];
#pragma unroll
    for (int ks = 0; ks < 2; ks++){
      const int kx = ks * 64;
      short8 af[4], bf[4];
#pragma unroll
      for (int f = 0; f < 4; f++) af[f] = *(const short8*)(A + (aoff[f] ^ kx));
#pragma unroll
      for (int f = 0; f < 4; f++) bf[f] = *(const short8*)(sB + (boff[f] ^ kx));
#pragma unroll
      for (int fn = 0; fn < 4; fn++)
#pragma unroll
        for (int fm = 0; fm < 4; fm++)
          acc[fm][fn] = __builtin_amdgcn_mfma_f32_16x16x32_bf16(af[fm], bf[fn], acc[fm][fn], 0, 0, 0);
    }
  }
  // epilogue: h = w * gelu(g) * u  (w folded here; dn becomes plain GEMM+atomicAdd)
#pragma unroll
  for (int fm = 0; fm < 4; fm++){
#pragma unroll
    for (int r = 0; r < 4; r++){
      int row = wm * 64 + fm * 16 + (lane >> 4) * 4 + r;
      if (row < cntL){
        float w = s_w[row];
        size_t base = (size_t)(p0 + row) * ID + (size_t)nt * 64 + wn * 32 + ln;
#pragma unroll
        for (int fn = 0; fn < 2; fn++){
          float g = acc[fm][fn][r];
          float u = acc[fm][fn + 2][r];
          hbuf[base + fn * 16] = __float2bfloat16(w * gelu_t(g) * u);
        }
      }
    }
  }
}

// -------- down: fused fp32 Wd staging + plain atomic scatter (w pre-applied in gu) --------
__global__ __launch_bounds__(256, 3)
void k_dn_f(const __hip_bfloat16* __restrict__ hbuf, const float* __restrict__ Wd,
            const int* __restrict__ row_tok, const int* __restrict__ off,
            float* __restrict__ out){
  __shared__ __align__(16) char sA[2][16384];  // [128 m][64 k], dbuf
  __shared__ __align__(16) char sB[16384];     // [128 n][64 k], slot^=swzB2(n)
  __shared__ int s_tok[128];

  const int bid = blockIdx.x;                // 640 = e(bid&7) x 5mt x 16nt
  const int e  = bid & 7;
  const int t  = bid >> 3;
  const int mt = t % 5;
  const int nt = t / 5;                      // 0..15
  const int o0 = off[e], cnt = off[e + 1] - o0;
  if (mt * 128 >= cnt) return;
  const int p0 = o0 + mt * 128;
  const int cntL = min(128, cnt - mt * 128);
  const int tid = threadIdx.x;
  const int wid = tid >> 6, lane = tid & 63;

  if (tid < 128){
    int p = min(p0 + tid, TT*2 - 1);
    s_tok[tid] = row_tok[p];
  }
  __syncthreads();

  const int sw = (((lane & 7) ^ (lane >> 3)) & 7) << 4;
  const char* asrc[4];
#pragma unroll
  for (int i = 0; i < 4; i++){
    int r = (wid * 4 + i) * 8 + (lane >> 3);
    int p = min(p0 + r, TT*2 - 1);
    asrc[i] = (const char*)hbuf + (size_t)p * 4096 + sw;
  }
  // B staging: thread -> 4 n x 8 consecutive k of Wd [k][HD n]
  const int n0 = (tid & 31) * 4;             // 0..124
  const int s0 = tid >> 5;                   // 0..7, k0 = s0*8
  const float* wsrc = Wd + (size_t)e * ID * HD + (size_t)(s0 * 8) * HD + (size_t)nt * 128 + n0;
  int bw[4];
#pragma unroll
  for (int j = 0; j < 4; j++){
    int np = n0 + j;
    bw[j] = np * 128 + (((s0 ^ swzB2(np)) & 7) << 4);
  }
  const int wm = wid >> 1, wn = wid & 1;
  const int kg = lane >> 4, ln = lane & 15;
  int aoff[4], boff[4];
#pragma unroll
  for (int f = 0; f < 4; f++){
    int m = wm * 64 + f * 16 + ln;
    aoff[f] = m * 128 + (((kg ^ (m & 7)) & 7) << 4);
    int n = wn * 64 + f * 16 + ln;
    boff[f] = n * 128 + (((kg ^ swzB2(n)) & 7) << 4);
  }

  f4 acc[4][4];
#pragma unroll
  for (int a = 0; a < 4; a++)
#pragma unroll
    for (int b = 0; b < 4; b++) acc[a][b] = f4{0,0,0,0};

#pragma unroll
  for (int i = 0; i < 4; i++) glds16(asrc[i], &sA[0][0] + (wid * 4 + i) * 1024);
  f4 rk[8];
#pragma unroll
  for (int i = 0; i < 8; i++) rk[i] = *(const f4*)(wsrc + (size_t)i * HD);

  for (int kt = 0; kt < 32; ++kt){
    softbar();
#pragma unroll
    for (int j = 0; j < 4; j++){
      *(uint4*)(sB + bw[j]) = uint4{ pk2(rk[0][j], rk[1][j]), pk2(rk[2][j], rk[3][j]),
                                     pk2(rk[4][j], rk[5][j]), pk2(rk[6][j], rk[7][j]) };
    }
    __builtin_amdgcn_sched_barrier(0);
    if (kt + 1 < 32){
      const int _o = (kt + 1) * 128;
      char* dst = &sA[(kt + 1) & 1][0] + (wid * 4) * 1024;
#pragma unroll
      for (int i = 0; i < 4; i++) glds16(asrc[i] + _o, dst + i * 1024);
    }
    __builtin_amdgcn_sched_barrier(0);
    if (kt + 1 < 32){
      const float* p = wsrc + (size_t)(kt + 1) * 64 * HD;
#pragma unroll
      for (int i = 0; i < 8; i++) rk[i] = *(const f4*)(p + (size_t)i * HD);
    }
    __builtin_amdgcn_sched_barrier(0);
    asm volatile("s_waitcnt lgkmcnt(0)" ::: "memory");
    __builtin_amdgcn_s_barrier();
    __builtin_amdgcn_sched_barrier(0);
    const char* A = &sA[kt & 1][0];
#pragma unroll
    for (int ks = 0; ks < 2; ks++){
      const int kx = ks * 64;
      short8 af[4], bf[4];
#pragma unroll
      for (int f = 0; f < 4; f++) af[f] = *(const short8*)(A + (aoff[f] ^ kx));
#pragma unroll
      for (int f = 0; f < 4; f++) bf[f] = *(const short8*)(sB + (boff[f] ^ kx));
#pragma unroll
      for (int fn = 0; fn < 4; fn++)
#pragma unroll
        for (int fm = 0; fm < 4; fm++)
          acc[fm][fn] = __builtin_amdgcn_mfma_f32_16x16x32_bf16(af[fm], bf[fn], acc[fm][fn], 0, 0, 0);
    }
  }
#pragma unroll
  for (int fm = 0; fm < 4; fm++){
#pragma unroll
    for (int r = 0; r < 4; r++){
      int row = wm * 64 + fm * 16 + (lane >> 4) * 4 + r;
      if (row < cntL){
        int tok = s_tok[row];
        float* ob = out + (size_t)tok * HD + (size_t)nt * 128 + wn * 64 + ln;
#pragma unroll
        for (int fn = 0; fn < 4; fn++)
          atomicAdd(ob + fn * 16, acc[fm][fn][r]);
      }
    }
  }
}

extern "C" void kernel_launch(void* const* d_in, const int* in_sizes, int n_in,
                              void* d_out, int out_size, void* d_ws, size_t ws_size,
                              hipStream_t stream){
  (void)in_sizes; (void)n_in; (void)out_size; (void)ws_size;
  const float* X  = (const float*)d_in[0];
  const float* RL = (const float*)d_in[1];
  const float* SC = (const float*)d_in[2];
  const float* Wg = (const float*)d_in[3];
  const float* Wu = (const float*)d_in[4];
  const float* Wd = (const float*)d_in[5];
  float* out = (float*)d_out;

  char* ws = (char*)d_ws;
  int*   rid     = (int*)(ws);
  float* rw      = (float*)(ws + 16384);
  int*   row_tok = (int*)(ws + 32768);
  float* row_w   = (float*)(ws + 49152);
  int*   off     = (int*)(ws + 65536);
  __hip_bfloat16* hbuf = (__hip_bfloat16*)(ws + 66560);                      // 16 MiB
  __hip_bfloat16* Xb   = (__hip_bfloat16*)(ws + 66560 + 16777216ull);        // 8 MiB

  hipMemsetAsync(d_out, 0, (size_t)TT * HD * sizeof(float), stream);
  k_cvtx <<<2048, 256, 0, stream>>>(X, Xb);
  k_route<<<TT / 256, 256, 0, stream>>>(RL, SC, rid, rw);
  k_lists<<<1, 64, 0, stream>>>(rid, rw, row_tok, row_w, off);
  k_gu_f<<<1280, 256, 0, stream>>>(Xb, Wg, Wu, row_tok, row_w, off, hbuf);
  k_dn_f<<< 640, 256, 0, stream>>>(hbuf, Wd, row_tok, off, out);
}